// Round 15
// baseline (302.639 us; speedup 1.0000x reference)
//
#include <hip/hip_runtime.h>
#include <hip/hip_bf16.h>

#define SEQ  4096
#define HID  768
#define NH   12
#define HD   64
#define QKVN 2304
#define KVB  32
#define SPLIT 4
#define NT   ((SEQ/SPLIT)/KVB)   // 32 kv-tiles per block
#define LOG2E  1.44269504f
#define SCALE2 (0.125f * LOG2E)

typedef __attribute__((ext_vector_type(8)))  short  short8;
typedef __attribute__((ext_vector_type(4)))  short  s16x4;
typedef __attribute__((ext_vector_type(4)))  float  f32x4;
typedef __attribute__((ext_vector_type(16))) float  f32x16;

static __device__ __forceinline__ unsigned short bf16b(float x) {
  __hip_bfloat16 h = __float2bfloat16(x);
  return *reinterpret_cast<unsigned short*>(&h);
}
static __device__ __forceinline__ unsigned pkbf(float lo, float hi) {
  return (unsigned)bf16b(lo) | ((unsigned)bf16b(hi) << 16);
}
// fast packed f32->bf16 pair (1 VALU op; T12 recipe — no builtin on gfx950)
static __device__ __forceinline__ unsigned cvtpk(float lo, float hi) {
  unsigned r;
  asm("v_cvt_pk_bf16_f32 %0, %1, %2" : "=v"(r) : "v"(lo), "v"(hi));
  return r;
}
static __device__ __forceinline__ void store4(__hip_bfloat16* p, float a, float b, float c, float d) {
  unsigned long long v = (unsigned long long)pkbf(a, b) | ((unsigned long long)pkbf(c, d) << 32);
  *reinterpret_cast<unsigned long long*>(p) = v;
}
static __device__ __forceinline__ void gload16(const void* g, void* l) {
  __builtin_amdgcn_global_load_lds(
      (const __attribute__((address_space(1))) void*)g,
      (__attribute__((address_space(3))) void*)l, 16, 0, 0);
}

#if __has_builtin(__builtin_amdgcn_exp2f)
#define EXP2(x) __builtin_amdgcn_exp2f(x)
#else
#define EXP2(x) __expf((x) * 0.6931472f)
#endif

// half-exchange: x[lane] = lane<32 ? a : b[lane^32] ; y[lane] = lane<32 ? a[lane^32] : b
static __device__ __forceinline__ void swap32(unsigned a, unsigned b, unsigned& x, unsigned& y) {
#if __has_builtin(__builtin_amdgcn_permlane32_swap)
  auto r = __builtin_amdgcn_permlane32_swap((int)a, (int)b, false, false);
  x = (unsigned)r[0]; y = (unsigned)r[1];
#else
  unsigned pa = (unsigned)__shfl_xor((int)a, 32);
  unsigned pb = (unsigned)__shfl_xor((int)b, 32);
  int hi = (int)((threadIdx.x & 63) >> 5);
  x = hi ? pb : a;
  y = hi ? b : pa;
#endif
}

static __device__ __forceinline__ void cvt_store(float* p, float v) { *p = v; }
static __device__ __forceinline__ void cvt_store(__hip_bfloat16* p, float v) { *p = __float2bfloat16(v); }

// ---------------- prep: fp32 -> bf16 casts + weight/bias concat + mask*log2e ----
__global__ __launch_bounds__(256) void prep_kernel(
    const float* __restrict__ hs,
    const float* __restrict__ qw, const float* __restrict__ kw,
    const float* __restrict__ vw, const float* __restrict__ ow,
    const float* __restrict__ qb, const float* __restrict__ kb,
    const float* __restrict__ vb, const float* __restrict__ msk,
    __hip_bfloat16* __restrict__ Xb,
    __hip_bfloat16* __restrict__ Wqkv,
    __hip_bfloat16* __restrict__ Wo,
    float* __restrict__ bqkv,
    float* __restrict__ mask2)
{
  const int NX = SEQ*HID/4, NW = QKVN*HID/4, NO = HID*HID/4, NB = QKVN/4, NM = SEQ/4;
  int idx = blockIdx.x*256 + threadIdx.x;
  if (idx < NX) {
    float4 v = ((const float4*)hs)[idx];
    store4(Xb + idx*4, v.x, v.y, v.z, v.w);
  } else if (idx < NX + NW) {
    int f = (idx - NX)*4;
    int row = f / HID, col = f - row*HID;
    const float* src = (row < HID)   ? qw + row*HID + col
                     : (row < 2*HID) ? kw + (row-HID)*HID + col
                     :                 vw + (row-2*HID)*HID + col;
    float4 v = *(const float4*)src;
    store4(Wqkv + f, v.x, v.y, v.z, v.w);
  } else if (idx < NX + NW + NO) {
    int li = idx - NX - NW;
    float4 v = ((const float4*)ow)[li];
    store4(Wo + li*4, v.x, v.y, v.z, v.w);
  } else if (idx < NX + NW + NO + NB) {
    int f = (idx - NX - NW - NO)*4;
    const float* src = (f < HID) ? qb + f : (f < 2*HID) ? kb + (f-HID) : vb + (f-2*HID);
    *(float4*)(bqkv + f) = *(const float4*)src;
  } else if (idx < NX + NW + NO + NB + NM) {
    int f = (idx - NX - NW - NO - NB)*4;
    float4 v = *(const float4*)(msk + f);
    float4 o; o.x = v.x*LOG2E; o.y = v.y*LOG2E; o.z = v.z*LOG2E; o.w = v.w*LOG2E;
    *(float4*)(mask2 + f) = o;
  }
}

// ---------------- GEMM  C[M][N] = A[M][K] * B[N][K]^T + bias -------------------
// m97 fragment layout + 3-buffer rotating LDS with counted vmcnt(4) barrier
// (verified win r12). iter t: issue tile t+2 gloads -> buf (t+2)%3 | compute
// buf t%3 | vmcnt(4) (retires exactly tile t+1's loads) + s_barrier.
#define GSTAGE(KT, BUF)                                        \
  {                                                            \
    const int k0s = (KT)*32;                                   \
    short* a_ = As + (BUF)*4096;                               \
    short* b_ = Bs + (BUF)*4096;                               \
    gload16(Ap0 + k0s, a_ + base0);                            \
    gload16(Ap1 + k0s, a_ + base1);                            \
    gload16(Bp0 + k0s, b_ + base0);                            \
    gload16(Bp1 + k0s, b_ + base1);                            \
  }

template <typename OutT, bool QSC>
__global__ __launch_bounds__(256) void gemm_nt(
    const __hip_bfloat16* __restrict__ A,
    const __hip_bfloat16* __restrict__ B,
    const float* __restrict__ bias,
    OutT* __restrict__ C, int N, int K)
{
  __shared__ __align__(16) short As[3*128*32];   // 24KB
  __shared__ __align__(16) short Bs[3*128*32];   // 24KB
  const int tid  = threadIdx.x;
  const int lane = tid & 63;
  const int w    = tid >> 6;
  const int m0   = blockIdx.y * 128;
  const int n0   = blockIdx.x * 128;
  const int wrow = w >> 1, wcol = w & 1;
  const int l15  = lane & 15;
  const int k8   = (lane >> 4) * 8;

  f32x4 acc[4][4] = {};

  const int base0 = w*512;
  const int base1 = (4+w)*512;
  const int f0 = base0 + lane*8, f1 = base1 + lane*8;
  const __hip_bfloat16* Ap0 = A + (long)(m0 + (f0>>5))*K + (f0&31);
  const __hip_bfloat16* Ap1 = A + (long)(m0 + (f1>>5))*K + (f1&31);
  const __hip_bfloat16* Bp0 = B + (long)(n0 + (f0>>5))*K + (f0&31);
  const __hip_bfloat16* Bp1 = B + (long)(n0 + (f1>>5))*K + (f1&31);

  const int nk = K/32;

  GSTAGE(0, 0);
  GSTAGE(1, 1);
  asm volatile("s_waitcnt vmcnt(4)" ::: "memory");   // tile 0 landed
  __builtin_amdgcn_s_barrier();
  __builtin_amdgcn_sched_barrier(0);

  int cur = 0, spc = 2;
  for (int t = 0; t < nk; ++t) {
    if (t + 2 < nk) GSTAGE(t+2, spc);
    __builtin_amdgcn_sched_barrier(0);

    const short* a = As + cur*4096;
    const short* b = Bs + cur*4096;
    short8 af[4], bfm[4];
#pragma unroll
    for (int mi = 0; mi < 4; ++mi)
      af[mi] = *(const short8*)&a[(wrow*64 + mi*16 + l15)*32 + k8];
#pragma unroll
    for (int ni = 0; ni < 4; ++ni)
      bfm[ni] = *(const short8*)&b[(wcol*64 + ni*16 + l15)*32 + k8];
#pragma unroll
    for (int mi = 0; mi < 4; ++mi)
#pragma unroll
      for (int ni = 0; ni < 4; ++ni)
        acc[mi][ni] = __builtin_amdgcn_mfma_f32_16x16x32_bf16(af[mi], bfm[ni], acc[mi][ni], 0, 0, 0);

    if (t + 2 < nk)
      asm volatile("s_waitcnt vmcnt(4) lgkmcnt(0)" ::: "memory");
    else
      asm volatile("s_waitcnt vmcnt(0) lgkmcnt(0)" ::: "memory");
    __builtin_amdgcn_s_barrier();
    __builtin_amdgcn_sched_barrier(0);

    cur = (cur == 2) ? 0 : cur + 1;
    spc = (spc == 2) ? 0 : spc + 1;
  }

  const int rbase = (lane >> 4) * 4;
#pragma unroll
  for (int mi = 0; mi < 4; ++mi)
#pragma unroll
    for (int ni = 0; ni < 4; ++ni) {
      int gm = m0 + wrow*64 + mi*16 + rbase;
      int gn = n0 + wcol*64 + ni*16 + l15;
      float bv = bias[gn];
      float sc = (QSC && gn < HID) ? SCALE2 : 1.0f;
#pragma unroll
      for (int r = 0; r < 4; ++r)
        cvt_store(&C[(long)(gm + r)*N + gn], (acc[mi][ni][r] + bv) * sc);
    }
}

// ---------------- flash attention, KV-split + fixed-max softmax ---------------
// grid (SEQ/128, NH, SPLIT=4) = 1536 blocks; 256 thr = 4 waves, each owns 32
// q-rows. NATURAL block mapping (r14's XCD remap EXPLODED traffic 56->218MB:
// default qt-fastest dispatch already L2-shares K/V — never remap this grid).
// r15 isolates the r14 pipeline changes: (1) K prefetch distance 2 via 4
// rotating Ks buffers, end-of-iter vmcnt(7) => K[t+1] in flight ~2 iters;
// (2) VT-write placed after QK^T. SPLIT=8 / chain-split QK^T / XCD-remap are
// measured regressions (r6,r11,r12,r14) — do not revisit.
#define ATTN_IT(T, KSC, KSS, VTC, VTN, MGC, MGN)                                \
  {                                                                             \
    short8 kf[4];                                                               \
    _Pragma("unroll")                                                           \
    for (int dc = 0; dc < 4; ++dc)                                              \
      kf[dc] = *(const short8*)&(KSC)[ql*64 + (((dc*2 + hi) ^ (ql & 7))*8)];    \
    if ((T) + 2 < NT)                                                           \
      gload16(kp + (long)((T)+2) * KVB * QKVN, (KSS) + wv*512);                 \
    __builtin_amdgcn_sched_barrier(0);                                          \
    f32x16 sacc = {};                                                           \
    _Pragma("unroll")                                                           \
    for (int dc = 0; dc < 4; ++dc)                                              \
      sacc = __builtin_amdgcn_mfma_f32_32x32x16_bf16(kf[dc], qf[dc], sacc, 0, 0, 0); \
    _Pragma("unroll")                                                           \
    for (int e = 0; e < 4; ++e) {                                               \
      unsigned w0 = (unsigned)(unsigned short)va[e] |                           \
                    ((unsigned)(unsigned short)vb[e] << 16);                    \
      *(unsigned*)&(VTN)[(vdb4 + e)*40 + vkv2] = w0;                            \
    }                                                                           \
    {                                                                           \
      const float* mrowN = mask2 + s0 + ((((T)+1) < NT) ? ((T)+1) : (T))*KVB;   \
      _Pragma("unroll")                                                         \
      for (int g = 0; g < 4; ++g)                                               \
        (MGN)[g] = *(const float4*)(mrowN + 8*g + 4*hi);                        \
      const long kn2 = (long)((((T)+2) < NT) ? ((T)+2) : (NT-1)) * KVB * QKVN;  \
      va = *(const s16x4*)(vsrc + kn2);                                         \
      vb = *(const s16x4*)(vsrc + kn2 + QKVN);                                  \
    }                                                                           \
    float p[16];                                                                \
    _Pragma("unroll")                                                           \
    for (int g = 0; g < 4; ++g) {                                               \
      p[4*g+0] = EXP2(sacc[4*g+0] + (MGC)[g].x);                                \
      p[4*g+1] = EXP2(sacc[4*g+1] + (MGC)[g].y);                                \
      p[4*g+2] = EXP2(sacc[4*g+2] + (MGC)[g].z);                                \
      p[4*g+3] = EXP2(sacc[4*g+3] + (MGC)[g].w);                                \
    }                                                                           \
    float sl0 = 0.f, sl1 = 0.f;                                                 \
    _Pragma("unroll")                                                           \
    for (int r = 0; r < 8; ++r) { sl0 += p[r]; sl1 += p[8+r]; }                 \
    lrun += sl0 + sl1;                                                          \
    unsigned pk[8];                                                             \
    _Pragma("unroll")                                                           \
    for (int u = 0; u < 8; ++u) pk[u] = cvtpk(p[2*u], p[2*u+1]);                \
    unsigned b0[4], b1[4];                                                      \
    swap32(pk[0], pk[2], b0[0], b0[2]);                                         \
    swap32(pk[1], pk[3], b0[1], b0[3]);                                         \
    swap32(pk[4], pk[6], b1[0], b1[2]);                                         \
    swap32(pk[5], pk[7], b1[1], b1[3]);                                         \
    union UU { unsigned u[4]; short8 s; };                                      \
    UU pb0{{b0[0], b0[1], b0[2], b0[3]}};                                       \
    UU pb1{{b1[0], b1[1], b1[2], b1[3]}};                                       \
    short8 a00 = *(const short8*)&(VTC)[(ql)*40      + hi*8];                   \
    short8 a01 = *(const short8*)&(VTC)[(ql)*40 + 16 + hi*8];                   \
    short8 a10 = *(const short8*)&(VTC)[(32+ql)*40      + hi*8];                \
    short8 a11 = *(const short8*)&(VTC)[(32+ql)*40 + 16 + hi*8];                \
    oacc[0] = __builtin_amdgcn_mfma_f32_32x32x16_bf16(a00, pb0.s, oacc[0], 0, 0, 0); \
    oacc[0] = __builtin_amdgcn_mfma_f32_32x32x16_bf16(a01, pb1.s, oacc[0], 0, 0, 0); \
    oacc[1] = __builtin_amdgcn_mfma_f32_32x32x16_bf16(a10, pb0.s, oacc[1], 0, 0, 0); \
    oacc[1] = __builtin_amdgcn_mfma_f32_32x32x16_bf16(a11, pb1.s, oacc[1], 0, 0, 0); \
    asm volatile("s_waitcnt vmcnt(7) lgkmcnt(0)" ::: "memory");                 \
    __builtin_amdgcn_s_barrier();                                               \
    __builtin_amdgcn_sched_barrier(0);                                          \
  }

__global__ __launch_bounds__(256, 4) void attn_fwd(
    const __hip_bfloat16* __restrict__ QKV,  // [SEQ][2304], Q cols pre-scaled
    const float* __restrict__ mask2,         // [SEQ], pre-scaled by log2e
    float* __restrict__ Oacc,                // [SEQ][HID]  (zeroed)
    float* __restrict__ Lacc)                // [NH][SEQ]   (zeroed)
{
  __shared__ __align__(16) char SMEM[26624];
  short* KsB = (short*)SMEM;            // 4 buffers x 2048 shorts (16KB)
  short* VTB = (short*)(SMEM + 16384);  // 2 buffers x 2560 shorts (10.25KB)
  float* Of  = (float*)SMEM;            // epilogue overlay [64][65] f32 (16.6KB)

  const int tid  = threadIdx.x;
  const int lane = tid & 63;
  const int wv   = tid >> 6;            // 0..3
  const int head = blockIdx.y;
  const int qt   = blockIdx.x;
  const int s0   = blockIdx.z * (SEQ/SPLIT);
  const int q0   = qt*128 + wv*32;
  const int ql   = lane & 31;
  const int hi   = lane >> 5;

  // Q fragments: B-frag for S^T: col=q=ql, k=d = dc*16 + hi*8 + j
  short8 qf[4];
  {
    const __hip_bfloat16* qrow = QKV + (long)(q0+ql)*QKVN + head*HD + hi*8;
#pragma unroll
    for (int dc = 0; dc < 4; ++dc)
      qf[dc] = *(const short8*)(qrow + dc*16);
  }

  // K staging: 256 chunks of 16B, one per thread; LDS chunk (krow,kcs) holds
  // global chunk kcs^(krow&7) (pre-swizzled source, m173).
  const __hip_bfloat16* kp;
  {
    int krow = tid >> 3, kcs = tid & 7;
    kp = QKV + (long)(s0 + krow)*QKVN + HID + head*HD + ((kcs ^ (krow & 7))*8);
  }

  // V staging: thread covers kv-pair (vkv2,vkv2+1), d-slice [vdb4, vdb4+4)
  const int vkv2 = (tid & 15)*2, vdb4 = (tid >> 4)*4;
  const __hip_bfloat16* vsrc = QKV + (long)(s0 + vkv2)*QKVN + 2*HID + head*HD + vdb4;

  f32x16 oacc[2] = {};
  float lrun = 0.0f;
  float4 mgA[4], mgB[4];

  short* K0 = KsB;            short* K1 = KsB + 2048;
  short* K2 = KsB + 4096;     short* K3 = KsB + 6144;
  short* V0 = VTB;            short* V1 = VTB + 2560;

  // ---- prologue: VT0 <- V[0]; gload K[0]->K0, K[1]->K1; mask[0]; V[1]->regs ----
  s16x4 va = *(const s16x4*)(vsrc);
  s16x4 vb = *(const s16x4*)(vsrc + QKVN);
#pragma unroll
  for (int e = 0; e < 4; ++e) {
    unsigned w0 = (unsigned)(unsigned short)va[e] | ((unsigned)(unsigned short)vb[e] << 16);
    *(unsigned*)&V0[(vdb4 + e)*40 + vkv2] = w0;
  }
  gload16(kp, K0 + wv*512);
  gload16(kp + (long)KVB*QKVN, K1 + wv*512);
  __builtin_amdgcn_sched_barrier(0);
  {
#pragma unroll
    for (int g = 0; g < 4; ++g)
      mgA[g] = *(const float4*)(mask2 + s0 + 8*g + 4*hi);
    const __hip_bfloat16* pv = vsrc + (long)KVB*QKVN;
    va = *(const s16x4*)(pv);
    vb = *(const s16x4*)(pv + QKVN);
  }
  asm volatile("s_waitcnt vmcnt(6) lgkmcnt(0)" ::: "memory");  // K[0] landed
  __builtin_amdgcn_s_barrier();
  __builtin_amdgcn_sched_barrier(0);

  for (int t = 0; t < NT; t += 4) {
    ATTN_IT(t,   K0, K2, V0, V1, mgA, mgB);
    ATTN_IT(t+1, K1, K3, V1, V0, mgB, mgA);
    ATTN_IT(t+2, K2, K0, V0, V1, mgA, mgB);
    ATTN_IT(t+3, K3, K1, V1, V0, mgB, mgA);
  }

  // ---- epilogue: O^T -> O transpose via [64][65] overlay, 2 phases ----
  float lp = lrun + __shfl_xor(lrun, 32);
  if (hi == 0)
    unsafeAtomicAdd(&Lacc[head*SEQ + q0 + ql], lp);

#pragma unroll
  for (int ph = 0; ph < 2; ++ph) {
    __syncthreads();
    if ((wv >> 1) == ph) {
      int row = (wv & 1)*32 + ql;
#pragma unroll
      for (int cb = 0; cb < 2; ++cb)
#pragma unroll
        for (int g = 0; g < 4; ++g)
#pragma unroll
          for (int r = 0; r < 4; ++r)
            Of[row*65 + cb*32 + 8*g + 4*hi + r] = oacc[cb][4*g + r];
    }
    __syncthreads();
    float* obase = Oacc + (long)(qt*128 + ph*64)*HID + head*HD + lane;
#pragma unroll 4
    for (int r = 0; r < 16; ++r) {
      int row = wv*16 + r;
      unsafeAtomicAdd(obase + (long)row*HID, Of[row*65 + lane]);
    }
  }
}

// ---------------- finalize: ctx = Oacc / l ------------------------------------
__global__ __launch_bounds__(256) void finalize_kernel(
    const float* __restrict__ Oacc, const float* __restrict__ Lacc,
    __hip_bfloat16* __restrict__ ctx)
{
  int idx = blockIdx.x*256 + threadIdx.x;
  int q  = idx / (HID/4);
  int c4 = (idx - q*(HID/4))*4;
  float inv = 1.0f / Lacc[(c4 >> 6)*SEQ + q];
  float4 o = *(const float4*)&Oacc[(long)q*HID + c4];
  store4(ctx + (long)q*HID + c4, o.x*inv, o.y*inv, o.z*inv, o.w*inv);
}

// ---------------- launcher ----------------------------------------------------
extern "C" void kernel_launch(void* const* d_in, const int* in_sizes, int n_in,
                              void* d_out, int out_size, void* d_ws, size_t ws_size,
                              hipStream_t stream) {
  const float* hs  = (const float*)d_in[0];
  const float* msk = (const float*)d_in[1];
  const float* qw  = (const float*)d_in[2];
  const float* qb  = (const float*)d_in[3];
  const float* kw  = (const float*)d_in[4];
  const float* kb  = (const float*)d_in[5];
  const float* vw  = (const float*)d_in[6];
  const float* vb  = (const float*)d_in[7];
  const float* ow  = (const float*)d_in[8];
  const float* ob  = (const float*)d_in[9];

  char* ws = (char*)d_ws;
  __hip_bfloat16* Xb   = (__hip_bfloat16*)(ws);                 // 6,291,456 B
  __hip_bfloat16* Wqkv = (__hip_bfloat16*)(ws + 6291456);       // 3,538,944 B
  __hip_bfloat16* Wo   = (__hip_bfloat16*)(ws + 9830400);       // 1,179,648 B
  float*          bqkv = (float*)         (ws + 11010048);      //     9,216 B
  __hip_bfloat16* QKV  = (__hip_bfloat16*)(ws + 11019264);      // 18,874,368 B
  __hip_bfloat16* Ctx  = (__hip_bfloat16*)(ws + 29893632);      // 6,291,456 B
  float*          Oacc = (float*)         (ws + 36185088);      // 12,582,912 B
  float*          Lacc = (float*)         (ws + 48768000);      //    196,608 B
  float*          Mask2= (float*)         (ws + 48964608);      //     16,384 B

  hipMemsetAsync(Oacc, 0, 12582912 + 196608, stream);

  {
    const int total = SEQ*HID/4 + QKVN*HID/4 + HID*HID/4 + QKVN/4 + SEQ/4;
    prep_kernel<<<(total + 255)/256, 256, 0, stream>>>(hs, qw, kw, vw, ow, qb, kb, vb, msk,
                                                       Xb, Wqkv, Wo, bqkv, Mask2);
  }
  gemm_nt<__hip_bfloat16, true><<<dim3(QKVN/128, SEQ/128), 256, 0, stream>>>(Xb, Wqkv, bqkv, QKV, QKVN, HID);
  attn_fwd<<<dim3(SEQ/128, NH, SPLIT), 256, 0, stream>>>(QKV, Mask2, Oacc, Lacc);
  finalize_kernel<<<(SEQ*HID/4)/256, 256, 0, stream>>>(Oacc, Lacc, Ctx);
  gemm_nt<float, false><<<dim3(HID/128, SEQ/128), 256, 0, stream>>>(Ctx, Wo, ob, (float*)d_out, HID, HID);
}

// Round 16
// 170.007 us; speedup vs baseline: 1.7802x; 1.7802x over previous
//
#include <hip/hip_runtime.h>
#include <hip/hip_bf16.h>

#define SEQ  4096
#define HID  768
#define NH   12
#define HD   64
#define QKVN 2304
#define KVB  32
#define SPLIT 4
#define NT   ((SEQ/SPLIT)/KVB)   // 32 kv-tiles per block
#define LOG2E  1.44269504f
#define SCALE2 (0.125f * LOG2E)

typedef __attribute__((ext_vector_type(8)))  short  short8;
typedef __attribute__((ext_vector_type(4)))  short  s16x4;
typedef __attribute__((ext_vector_type(4)))  float  f32x4;
typedef __attribute__((ext_vector_type(16))) float  f32x16;

static __device__ __forceinline__ unsigned short bf16b(float x) {
  __hip_bfloat16 h = __float2bfloat16(x);
  return *reinterpret_cast<unsigned short*>(&h);
}
static __device__ __forceinline__ unsigned pkbf(float lo, float hi) {
  return (unsigned)bf16b(lo) | ((unsigned)bf16b(hi) << 16);
}
// fast packed f32->bf16 pair (1 VALU op; T12 recipe — no builtin on gfx950)
static __device__ __forceinline__ unsigned cvtpk(float lo, float hi) {
  unsigned r;
  asm("v_cvt_pk_bf16_f32 %0, %1, %2" : "=v"(r) : "v"(lo), "v"(hi));
  return r;
}
static __device__ __forceinline__ void store4(__hip_bfloat16* p, float a, float b, float c, float d) {
  unsigned long long v = (unsigned long long)pkbf(a, b) | ((unsigned long long)pkbf(c, d) << 32);
  *reinterpret_cast<unsigned long long*>(p) = v;
}
static __device__ __forceinline__ void gload16(const void* g, void* l) {
  __builtin_amdgcn_global_load_lds(
      (const __attribute__((address_space(1))) void*)g,
      (__attribute__((address_space(3))) void*)l, 16, 0, 0);
}

#if __has_builtin(__builtin_amdgcn_exp2f)
#define EXP2(x) __builtin_amdgcn_exp2f(x)
#else
#define EXP2(x) __expf((x) * 0.6931472f)
#endif

// half-exchange: x[lane] = lane<32 ? a : b[lane^32] ; y[lane] = lane<32 ? a[lane^32] : b
static __device__ __forceinline__ void swap32(unsigned a, unsigned b, unsigned& x, unsigned& y) {
#if __has_builtin(__builtin_amdgcn_permlane32_swap)
  auto r = __builtin_amdgcn_permlane32_swap((int)a, (int)b, false, false);
  x = (unsigned)r[0]; y = (unsigned)r[1];
#else
  unsigned pa = (unsigned)__shfl_xor((int)a, 32);
  unsigned pb = (unsigned)__shfl_xor((int)b, 32);
  int hi = (int)((threadIdx.x & 63) >> 5);
  x = hi ? pb : a;
  y = hi ? b : pa;
#endif
}

static __device__ __forceinline__ void cvt_store(float* p, float v) { *p = v; }
static __device__ __forceinline__ void cvt_store(__hip_bfloat16* p, float v) { *p = __float2bfloat16(v); }

// ---------------- prep: fp32 -> bf16 casts + weight/bias concat + mask*log2e ----
__global__ __launch_bounds__(256) void prep_kernel(
    const float* __restrict__ hs,
    const float* __restrict__ qw, const float* __restrict__ kw,
    const float* __restrict__ vw, const float* __restrict__ ow,
    const float* __restrict__ qb, const float* __restrict__ kb,
    const float* __restrict__ vb, const float* __restrict__ msk,
    __hip_bfloat16* __restrict__ Xb,
    __hip_bfloat16* __restrict__ Wqkv,
    __hip_bfloat16* __restrict__ Wo,
    float* __restrict__ bqkv,
    float* __restrict__ mask2)
{
  const int NX = SEQ*HID/4, NW = QKVN*HID/4, NO = HID*HID/4, NB = QKVN/4, NM = SEQ/4;
  int idx = blockIdx.x*256 + threadIdx.x;
  if (idx < NX) {
    float4 v = ((const float4*)hs)[idx];
    store4(Xb + idx*4, v.x, v.y, v.z, v.w);
  } else if (idx < NX + NW) {
    int f = (idx - NX)*4;
    int row = f / HID, col = f - row*HID;
    const float* src = (row < HID)   ? qw + row*HID + col
                     : (row < 2*HID) ? kw + (row-HID)*HID + col
                     :                 vw + (row-2*HID)*HID + col;
    float4 v = *(const float4*)src;
    store4(Wqkv + f, v.x, v.y, v.z, v.w);
  } else if (idx < NX + NW + NO) {
    int li = idx - NX - NW;
    float4 v = ((const float4*)ow)[li];
    store4(Wo + li*4, v.x, v.y, v.z, v.w);
  } else if (idx < NX + NW + NO + NB) {
    int f = (idx - NX - NW - NO)*4;
    const float* src = (f < HID) ? qb + f : (f < 2*HID) ? kb + (f-HID) : vb + (f-2*HID);
    *(float4*)(bqkv + f) = *(const float4*)src;
  } else if (idx < NX + NW + NO + NB + NM) {
    int f = (idx - NX - NW - NO - NB)*4;
    float4 v = *(const float4*)(msk + f);
    float4 o; o.x = v.x*LOG2E; o.y = v.y*LOG2E; o.z = v.z*LOG2E; o.w = v.w*LOG2E;
    *(float4*)(mask2 + f) = o;
  }
}

// ---------------- GEMM  C[M][N] = A[M][K] * B[N][K]^T + bias -------------------
// m97 fragment layout + 3-buffer rotating LDS with counted vmcnt(4) barrier
// (verified win r12: non-attn time 62->53us). iter t: issue tile t+2 gloads ->
// buf (t+2)%3 | compute buf t%3 | vmcnt(4) (retires exactly tile t+1's loads)
// + s_barrier. Buffer reuse distance 3 + barrier => no DMA/read race.
// QSC: scale (acc+bias) of columns gn<HID by SCALE2 (folds softmax scale into Q).
#define GSTAGE(KT, BUF)                                        \
  {                                                            \
    const int k0s = (KT)*32;                                   \
    short* a_ = As + (BUF)*4096;                               \
    short* b_ = Bs + (BUF)*4096;                               \
    gload16(Ap0 + k0s, a_ + base0);                            \
    gload16(Ap1 + k0s, a_ + base1);                            \
    gload16(Bp0 + k0s, b_ + base0);                            \
    gload16(Bp1 + k0s, b_ + base1);                            \
  }

template <typename OutT, bool QSC>
__global__ __launch_bounds__(256) void gemm_nt(
    const __hip_bfloat16* __restrict__ A,
    const __hip_bfloat16* __restrict__ B,
    const float* __restrict__ bias,
    OutT* __restrict__ C, int N, int K)
{
  __shared__ __align__(16) short As[3*128*32];   // 24KB
  __shared__ __align__(16) short Bs[3*128*32];   // 24KB
  const int tid  = threadIdx.x;
  const int lane = tid & 63;
  const int w    = tid >> 6;
  const int m0   = blockIdx.y * 128;
  const int n0   = blockIdx.x * 128;
  const int wrow = w >> 1, wcol = w & 1;
  const int l15  = lane & 15;
  const int k8   = (lane >> 4) * 8;

  f32x4 acc[4][4] = {};

  const int base0 = w*512;
  const int base1 = (4+w)*512;
  const int f0 = base0 + lane*8, f1 = base1 + lane*8;
  const __hip_bfloat16* Ap0 = A + (long)(m0 + (f0>>5))*K + (f0&31);
  const __hip_bfloat16* Ap1 = A + (long)(m0 + (f1>>5))*K + (f1&31);
  const __hip_bfloat16* Bp0 = B + (long)(n0 + (f0>>5))*K + (f0&31);
  const __hip_bfloat16* Bp1 = B + (long)(n0 + (f1>>5))*K + (f1&31);

  const int nk = K/32;

  GSTAGE(0, 0);
  GSTAGE(1, 1);
  asm volatile("s_waitcnt vmcnt(4)" ::: "memory");   // tile 0 landed
  __builtin_amdgcn_s_barrier();
  __builtin_amdgcn_sched_barrier(0);

  int cur = 0, spc = 2;
  for (int t = 0; t < nk; ++t) {
    if (t + 2 < nk) GSTAGE(t+2, spc);
    __builtin_amdgcn_sched_barrier(0);

    const short* a = As + cur*4096;
    const short* b = Bs + cur*4096;
    short8 af[4], bfm[4];
#pragma unroll
    for (int mi = 0; mi < 4; ++mi)
      af[mi] = *(const short8*)&a[(wrow*64 + mi*16 + l15)*32 + k8];
#pragma unroll
    for (int ni = 0; ni < 4; ++ni)
      bfm[ni] = *(const short8*)&b[(wcol*64 + ni*16 + l15)*32 + k8];
#pragma unroll
    for (int mi = 0; mi < 4; ++mi)
#pragma unroll
      for (int ni = 0; ni < 4; ++ni)
        acc[mi][ni] = __builtin_amdgcn_mfma_f32_16x16x32_bf16(af[mi], bfm[ni], acc[mi][ni], 0, 0, 0);

    if (t + 2 < nk)
      asm volatile("s_waitcnt vmcnt(4) lgkmcnt(0)" ::: "memory");
    else
      asm volatile("s_waitcnt vmcnt(0) lgkmcnt(0)" ::: "memory");
    __builtin_amdgcn_s_barrier();
    __builtin_amdgcn_sched_barrier(0);

    cur = (cur == 2) ? 0 : cur + 1;
    spc = (spc == 2) ? 0 : spc + 1;
  }

  const int rbase = (lane >> 4) * 4;
#pragma unroll
  for (int mi = 0; mi < 4; ++mi)
#pragma unroll
    for (int ni = 0; ni < 4; ++ni) {
      int gm = m0 + wrow*64 + mi*16 + rbase;
      int gn = n0 + wcol*64 + ni*16 + l15;
      float bv = bias[gn];
      float sc = (QSC && gn < HID) ? SCALE2 : 1.0f;
#pragma unroll
      for (int r = 0; r < 4; ++r)
        cvt_store(&C[(long)(gm + r)*N + gn], (acc[mi][ni][r] + bv) * sc);
    }
}

// ---------------- flash attention, KV-split + fixed-max softmax ---------------
// grid (SEQ/128, NH, SPLIT=4) = 1536 blocks; 256 thr = 4 waves, each owns 32
// q-rows. EXACT r13 structure (verified best: attn 110.6us, total 170.0us):
// counted-vmcnt loop unrolled x2, single-chain QK^T, cvtpk P-pack, natural
// block mapping. Measured regressions — do not revisit: SPLIT=8 (r6,r11),
// chain-split QK^T (r12, AGPR spill), prep-fused zeroing (r12), XCD remap
// (r14, L2 locality destroyed), 4-buffer/VT-after-QKT pipeline (r14/r15,
// register spill -> 300MB scratch traffic).
#define ATTN_ITER(T, KSC, KSN, VTC, VTN, MGC, MGN)                              \
  {                                                                             \
    _Pragma("unroll")                                                           \
    for (int e = 0; e < 4; ++e) {                                               \
      unsigned w0 = (unsigned)(unsigned short)va[e] |                           \
                    ((unsigned)(unsigned short)vb[e] << 16);                    \
      *(unsigned*)&(VTN)[(vdb4 + e)*40 + vkv2] = w0;                            \
    }                                                                           \
    if ((T) + 1 < NT)                                                           \
      gload16(kp + (long)((T)+1) * KVB * QKVN, (KSN) + wv*512);                 \
    __builtin_amdgcn_sched_barrier(0);                                          \
    {                                                                           \
      const float* mrowN = mask2 + s0 + ((((T)+1) < NT) ? ((T)+1) : (T))*KVB;   \
      _Pragma("unroll")                                                         \
      for (int g = 0; g < 4; ++g)                                               \
        (MGN)[g] = *(const float4*)(mrowN + 8*g + 4*hi);                        \
      const long kn2 = (long)((((T)+2) < NT) ? ((T)+2) : (NT-1)) * KVB * QKVN;  \
      va = *(const s16x4*)(vsrc + kn2);                                         \
      vb = *(const s16x4*)(vsrc + kn2 + QKVN);                                  \
    }                                                                           \
    short8 kf[4];                                                               \
    _Pragma("unroll")                                                           \
    for (int dc = 0; dc < 4; ++dc)                                              \
      kf[dc] = *(const short8*)&(KSC)[ql*64 + (((dc*2 + hi) ^ (ql & 7))*8)];    \
    f32x16 sacc = {};                                                           \
    _Pragma("unroll")                                                           \
    for (int dc = 0; dc < 4; ++dc)                                              \
      sacc = __builtin_amdgcn_mfma_f32_32x32x16_bf16(kf[dc], qf[dc], sacc, 0, 0, 0); \
    float p[16];                                                                \
    _Pragma("unroll")                                                           \
    for (int g = 0; g < 4; ++g) {                                               \
      p[4*g+0] = EXP2(sacc[4*g+0] + (MGC)[g].x);                                \
      p[4*g+1] = EXP2(sacc[4*g+1] + (MGC)[g].y);                                \
      p[4*g+2] = EXP2(sacc[4*g+2] + (MGC)[g].z);                                \
      p[4*g+3] = EXP2(sacc[4*g+3] + (MGC)[g].w);                                \
    }                                                                           \
    float sl0 = 0.f, sl1 = 0.f;                                                 \
    _Pragma("unroll")                                                           \
    for (int r = 0; r < 8; ++r) { sl0 += p[r]; sl1 += p[8+r]; }                 \
    lrun += sl0 + sl1;                                                          \
    unsigned pk[8];                                                             \
    _Pragma("unroll")                                                           \
    for (int u = 0; u < 8; ++u) pk[u] = cvtpk(p[2*u], p[2*u+1]);                \
    unsigned b0[4], b1[4];                                                      \
    swap32(pk[0], pk[2], b0[0], b0[2]);                                         \
    swap32(pk[1], pk[3], b0[1], b0[3]);                                         \
    swap32(pk[4], pk[6], b1[0], b1[2]);                                         \
    swap32(pk[5], pk[7], b1[1], b1[3]);                                         \
    union UU { unsigned u[4]; short8 s; };                                      \
    UU pb0{{b0[0], b0[1], b0[2], b0[3]}};                                       \
    UU pb1{{b1[0], b1[1], b1[2], b1[3]}};                                       \
    short8 a00 = *(const short8*)&(VTC)[(ql)*40      + hi*8];                   \
    short8 a01 = *(const short8*)&(VTC)[(ql)*40 + 16 + hi*8];                   \
    short8 a10 = *(const short8*)&(VTC)[(32+ql)*40      + hi*8];                \
    short8 a11 = *(const short8*)&(VTC)[(32+ql)*40 + 16 + hi*8];                \
    oacc[0] = __builtin_amdgcn_mfma_f32_32x32x16_bf16(a00, pb0.s, oacc[0], 0, 0, 0); \
    oacc[0] = __builtin_amdgcn_mfma_f32_32x32x16_bf16(a01, pb1.s, oacc[0], 0, 0, 0); \
    oacc[1] = __builtin_amdgcn_mfma_f32_32x32x16_bf16(a10, pb0.s, oacc[1], 0, 0, 0); \
    oacc[1] = __builtin_amdgcn_mfma_f32_32x32x16_bf16(a11, pb1.s, oacc[1], 0, 0, 0); \
    asm volatile("s_waitcnt vmcnt(6) lgkmcnt(0)" ::: "memory");                 \
    __builtin_amdgcn_s_barrier();                                               \
    __builtin_amdgcn_sched_barrier(0);                                          \
  }

__global__ __launch_bounds__(256, 4) void attn_fwd(
    const __hip_bfloat16* __restrict__ QKV,  // [SEQ][2304], Q cols pre-scaled
    const float* __restrict__ mask2,         // [SEQ], pre-scaled by log2e
    float* __restrict__ Oacc,                // [SEQ][HID]  (zeroed)
    float* __restrict__ Lacc)                // [NH][SEQ]   (zeroed)
{
  __shared__ __align__(16) char SMEM[18432];
  short* KsB = (short*)SMEM;            // 2 buffers x 2048 shorts (8KB)
  short* VTB = (short*)(SMEM + 8192);   // 2 buffers x 2560 shorts (10.25KB)
  float* Of  = (float*)SMEM;            // epilogue overlay [64][65] f32 (16.6KB)

  const int tid  = threadIdx.x;
  const int lane = tid & 63;
  const int wv   = tid >> 6;            // 0..3
  const int head = blockIdx.y;
  const int qt   = blockIdx.x;
  const int s0   = blockIdx.z * (SEQ/SPLIT);
  const int q0   = qt*128 + wv*32;
  const int ql   = lane & 31;
  const int hi   = lane >> 5;

  // Q fragments: B-frag for S^T: col=q=ql, k=d = dc*16 + hi*8 + j
  short8 qf[4];
  {
    const __hip_bfloat16* qrow = QKV + (long)(q0+ql)*QKVN + head*HD + hi*8;
#pragma unroll
    for (int dc = 0; dc < 4; ++dc)
      qf[dc] = *(const short8*)(qrow + dc*16);
  }

  // K staging: 256 chunks of 16B, one per thread; LDS chunk (krow,kcs) holds
  // global chunk kcs^(krow&7) (pre-swizzled source, m173).
  const __hip_bfloat16* kp;
  {
    int krow = tid >> 3, kcs = tid & 7;
    kp = QKV + (long)(s0 + krow)*QKVN + HID + head*HD + ((kcs ^ (krow & 7))*8);
  }

  // V staging: thread covers kv-pair (vkv2,vkv2+1), d-slice [vdb4, vdb4+4)
  const int vkv2 = (tid & 15)*2, vdb4 = (tid >> 4)*4;
  const __hip_bfloat16* vsrc = QKV + (long)(s0 + vkv2)*QKVN + 2*HID + head*HD + vdb4;

  f32x16 oacc[2] = {};
  float lrun = 0.0f;
  float4 mgA[4], mgB[4];

  // ---- prologue: VT buf0 <- V[0]; gload K[0]->Ks buf0; prefetch mask[0], V[1] ----
  s16x4 va = *(const s16x4*)(vsrc);
  s16x4 vb = *(const s16x4*)(vsrc + QKVN);
#pragma unroll
  for (int e = 0; e < 4; ++e) {
    unsigned w0 = (unsigned)(unsigned short)va[e] | ((unsigned)(unsigned short)vb[e] << 16);
    *(unsigned*)&VTB[(vdb4 + e)*40 + vkv2] = w0;
  }
  gload16(kp, KsB + wv*512);
  __builtin_amdgcn_sched_barrier(0);
  {
#pragma unroll
    for (int g = 0; g < 4; ++g)
      mgA[g] = *(const float4*)(mask2 + s0 + 8*g + 4*hi);
    const __hip_bfloat16* pv = vsrc + (long)KVB*QKVN;
    va = *(const s16x4*)(pv);
    vb = *(const s16x4*)(pv + QKVN);
  }
  asm volatile("s_waitcnt vmcnt(6) lgkmcnt(0)" ::: "memory");
  __builtin_amdgcn_s_barrier();
  __builtin_amdgcn_sched_barrier(0);

  for (int t = 0; t < NT; t += 2) {
    ATTN_ITER(t,   KsB,        KsB + 2048, VTB,        VTB + 2560, mgA, mgB);
    ATTN_ITER(t+1, KsB + 2048, KsB,        VTB + 2560, VTB,        mgB, mgA);
  }

  // ---- epilogue: O^T -> O transpose via [64][65] overlay, 2 phases ----
  float lp = lrun + __shfl_xor(lrun, 32);
  if (hi == 0)
    unsafeAtomicAdd(&Lacc[head*SEQ + q0 + ql], lp);

#pragma unroll
  for (int ph = 0; ph < 2; ++ph) {
    __syncthreads();
    if ((wv >> 1) == ph) {
      int row = (wv & 1)*32 + ql;
#pragma unroll
      for (int cb = 0; cb < 2; ++cb)
#pragma unroll
        for (int g = 0; g < 4; ++g)
#pragma unroll
          for (int r = 0; r < 4; ++r)
            Of[row*65 + cb*32 + 8*g + 4*hi + r] = oacc[cb][4*g + r];
    }
    __syncthreads();
    float* obase = Oacc + (long)(qt*128 + ph*64)*HID + head*HD + lane;
#pragma unroll 4
    for (int r = 0; r < 16; ++r) {
      int row = wv*16 + r;
      unsafeAtomicAdd(obase + (long)row*HID, Of[row*65 + lane]);
    }
  }
}

// ---------------- finalize: ctx = Oacc / l ------------------------------------
__global__ __launch_bounds__(256) void finalize_kernel(
    const float* __restrict__ Oacc, const float* __restrict__ Lacc,
    __hip_bfloat16* __restrict__ ctx)
{
  int idx = blockIdx.x*256 + threadIdx.x;
  int q  = idx / (HID/4);
  int c4 = (idx - q*(HID/4))*4;
  float inv = 1.0f / Lacc[(c4 >> 6)*SEQ + q];
  float4 o = *(const float4*)&Oacc[(long)q*HID + c4];
  store4(ctx + (long)q*HID + c4, o.x*inv, o.y*inv, o.z*inv, o.w*inv);
}

// ---------------- launcher ----------------------------------------------------
extern "C" void kernel_launch(void* const* d_in, const int* in_sizes, int n_in,
                              void* d_out, int out_size, void* d_ws, size_t ws_size,
                              hipStream_t stream) {
  const float* hs  = (const float*)d_in[0];
  const float* msk = (const float*)d_in[1];
  const float* qw  = (const float*)d_in[2];
  const float* qb  = (const float*)d_in[3];
  const float* kw  = (const float*)d_in[4];
  const float* kb  = (const float*)d_in[5];
  const float* vw  = (const float*)d_in[6];
  const float* vb  = (const float*)d_in[7];
  const float* ow  = (const float*)d_in[8];
  const float* ob  = (const float*)d_in[9];

  char* ws = (char*)d_ws;
  __hip_bfloat16* Xb   = (__hip_bfloat16*)(ws);                 // 6,291,456 B
  __hip_bfloat16* Wqkv = (__hip_bfloat16*)(ws + 6291456);       // 3,538,944 B
  __hip_bfloat16* Wo   = (__hip_bfloat16*)(ws + 9830400);       // 1,179,648 B
  float*          bqkv = (float*)         (ws + 11010048);      //     9,216 B
  __hip_bfloat16* QKV  = (__hip_bfloat16*)(ws + 11019264);      // 18,874,368 B
  __hip_bfloat16* Ctx  = (__hip_bfloat16*)(ws + 29893632);      // 6,291,456 B
  float*          Oacc = (float*)         (ws + 36185088);      // 12,582,912 B
  float*          Lacc = (float*)         (ws + 48768000);      //    196,608 B
  float*          Mask2= (float*)         (ws + 48964608);      //     16,384 B

  hipMemsetAsync(Oacc, 0, 12582912 + 196608, stream);

  {
    const int total = SEQ*HID/4 + QKVN*HID/4 + HID*HID/4 + QKVN/4 + SEQ/4;
    prep_kernel<<<(total + 255)/256, 256, 0, stream>>>(hs, qw, kw, vw, ow, qb, kb, vb, msk,
                                                       Xb, Wqkv, Wo, bqkv, Mask2);
  }
  gemm_nt<__hip_bfloat16, true><<<dim3(QKVN/128, SEQ/128), 256, 0, stream>>>(Xb, Wqkv, bqkv, QKV, QKVN, HID);
  attn_fwd<<<dim3(SEQ/128, NH, SPLIT), 256, 0, stream>>>(QKV, Mask2, Oacc, Lacc);
  finalize_kernel<<<(SEQ*HID/4)/256, 256, 0, stream>>>(Oacc, Lacc, Ctx);
  gemm_nt<float, false><<<dim3(HID/128, SEQ/128), 256, 0, stream>>>(Ctx, Wo, ob, (float*)d_out, HID, HID);
}

// Round 17
// 161.407 us; speedup vs baseline: 1.8750x; 1.0533x over previous
//
#include <hip/hip_runtime.h>
#include <hip/hip_bf16.h>

#define SEQ  4096
#define HID  768
#define NH   12
#define HD   64
#define QKVN 2304
#define KVB  32
#define SPLIT 2
#define NT   ((SEQ/SPLIT)/KVB)   // 64 kv-tiles per block
#define LOG2E  1.44269504f
#define SCALE2 (0.125f * LOG2E)

typedef __attribute__((ext_vector_type(8)))  short  short8;
typedef __attribute__((ext_vector_type(4)))  short  s16x4;
typedef __attribute__((ext_vector_type(4)))  float  f32x4;
typedef __attribute__((ext_vector_type(16))) float  f32x16;

static __device__ __forceinline__ unsigned short bf16b(float x) {
  __hip_bfloat16 h = __float2bfloat16(x);
  return *reinterpret_cast<unsigned short*>(&h);
}
static __device__ __forceinline__ unsigned pkbf(float lo, float hi) {
  return (unsigned)bf16b(lo) | ((unsigned)bf16b(hi) << 16);
}
// fast packed f32->bf16 pair (1 VALU op; T12 recipe — no builtin on gfx950)
static __device__ __forceinline__ unsigned cvtpk(float lo, float hi) {
  unsigned r;
  asm("v_cvt_pk_bf16_f32 %0, %1, %2" : "=v"(r) : "v"(lo), "v"(hi));
  return r;
}
static __device__ __forceinline__ void store4(__hip_bfloat16* p, float a, float b, float c, float d) {
  unsigned long long v = (unsigned long long)pkbf(a, b) | ((unsigned long long)pkbf(c, d) << 32);
  *reinterpret_cast<unsigned long long*>(p) = v;
}
static __device__ __forceinline__ void gload16(const void* g, void* l) {
  __builtin_amdgcn_global_load_lds(
      (const __attribute__((address_space(1))) void*)g,
      (__attribute__((address_space(3))) void*)l, 16, 0, 0);
}

#if __has_builtin(__builtin_amdgcn_exp2f)
#define EXP2(x) __builtin_amdgcn_exp2f(x)
#else
#define EXP2(x) __expf((x) * 0.6931472f)
#endif

// half-exchange: x[lane] = lane<32 ? a : b[lane^32] ; y[lane] = lane<32 ? a[lane^32] : b
static __device__ __forceinline__ void swap32(unsigned a, unsigned b, unsigned& x, unsigned& y) {
#if __has_builtin(__builtin_amdgcn_permlane32_swap)
  auto r = __builtin_amdgcn_permlane32_swap((int)a, (int)b, false, false);
  x = (unsigned)r[0]; y = (unsigned)r[1];
#else
  unsigned pa = (unsigned)__shfl_xor((int)a, 32);
  unsigned pb = (unsigned)__shfl_xor((int)b, 32);
  int hi = (int)((threadIdx.x & 63) >> 5);
  x = hi ? pb : a;
  y = hi ? b : pa;
#endif
}

static __device__ __forceinline__ void cvt_store(float* p, float v) { *p = v; }
static __device__ __forceinline__ void cvt_store(__hip_bfloat16* p, float v) { *p = __float2bfloat16(v); }

// ---------------- prep: fp32 -> bf16 casts + weight/bias concat + mask*log2e ----
__global__ __launch_bounds__(256) void prep_kernel(
    const float* __restrict__ hs,
    const float* __restrict__ qw, const float* __restrict__ kw,
    const float* __restrict__ vw, const float* __restrict__ ow,
    const float* __restrict__ qb, const float* __restrict__ kb,
    const float* __restrict__ vb, const float* __restrict__ msk,
    __hip_bfloat16* __restrict__ Xb,
    __hip_bfloat16* __restrict__ Wqkv,
    __hip_bfloat16* __restrict__ Wo,
    float* __restrict__ bqkv,
    float* __restrict__ mask2)
{
  const int NX = SEQ*HID/4, NW = QKVN*HID/4, NO = HID*HID/4, NB = QKVN/4, NM = SEQ/4;
  int idx = blockIdx.x*256 + threadIdx.x;
  if (idx < NX) {
    float4 v = ((const float4*)hs)[idx];
    store4(Xb + idx*4, v.x, v.y, v.z, v.w);
  } else if (idx < NX + NW) {
    int f = (idx - NX)*4;
    int row = f / HID, col = f - row*HID;
    const float* src = (row < HID)   ? qw + row*HID + col
                     : (row < 2*HID) ? kw + (row-HID)*HID + col
                     :                 vw + (row-2*HID)*HID + col;
    float4 v = *(const float4*)src;
    store4(Wqkv + f, v.x, v.y, v.z, v.w);
  } else if (idx < NX + NW + NO) {
    int li = idx - NX - NW;
    float4 v = ((const float4*)ow)[li];
    store4(Wo + li*4, v.x, v.y, v.z, v.w);
  } else if (idx < NX + NW + NO + NB) {
    int f = (idx - NX - NW - NO)*4;
    const float* src = (f < HID) ? qb + f : (f < 2*HID) ? kb + (f-HID) : vb + (f-2*HID);
    *(float4*)(bqkv + f) = *(const float4*)src;
  } else if (idx < NX + NW + NO + NB + NM) {
    int f = (idx - NX - NW - NO - NB)*4;
    float4 v = *(const float4*)(msk + f);
    float4 o; o.x = v.x*LOG2E; o.y = v.y*LOG2E; o.z = v.z*LOG2E; o.w = v.w*LOG2E;
    *(float4*)(mask2 + f) = o;
  }
}

// ---------------- GEMM  C[M][N] = A[M][K] * B[N][K]^T + bias -------------------
// m97 fragment layout + 3-buffer rotating LDS with counted vmcnt(4) barrier
// (verified win r12: non-attn time 62->53us). iter t: issue tile t+2 gloads ->
// buf (t+2)%3 | compute buf t%3 | vmcnt(4) (retires exactly tile t+1's loads)
// + s_barrier. Buffer reuse distance 3 + barrier => no DMA/read race.
// QSC: scale (acc+bias) of columns gn<HID by SCALE2 (folds softmax scale into Q).
#define GSTAGE(KT, BUF)                                        \
  {                                                            \
    const int k0s = (KT)*32;                                   \
    short* a_ = As + (BUF)*4096;                               \
    short* b_ = Bs + (BUF)*4096;                               \
    gload16(Ap0 + k0s, a_ + base0);                            \
    gload16(Ap1 + k0s, a_ + base1);                            \
    gload16(Bp0 + k0s, b_ + base0);                            \
    gload16(Bp1 + k0s, b_ + base1);                            \
  }

template <typename OutT, bool QSC>
__global__ __launch_bounds__(256) void gemm_nt(
    const __hip_bfloat16* __restrict__ A,
    const __hip_bfloat16* __restrict__ B,
    const float* __restrict__ bias,
    OutT* __restrict__ C, int N, int K)
{
  __shared__ __align__(16) short As[3*128*32];   // 24KB
  __shared__ __align__(16) short Bs[3*128*32];   // 24KB
  const int tid  = threadIdx.x;
  const int lane = tid & 63;
  const int w    = tid >> 6;
  const int m0   = blockIdx.y * 128;
  const int n0   = blockIdx.x * 128;
  const int wrow = w >> 1, wcol = w & 1;
  const int l15  = lane & 15;
  const int k8   = (lane >> 4) * 8;

  f32x4 acc[4][4] = {};

  const int base0 = w*512;
  const int base1 = (4+w)*512;
  const int f0 = base0 + lane*8, f1 = base1 + lane*8;
  const __hip_bfloat16* Ap0 = A + (long)(m0 + (f0>>5))*K + (f0&31);
  const __hip_bfloat16* Ap1 = A + (long)(m0 + (f1>>5))*K + (f1&31);
  const __hip_bfloat16* Bp0 = B + (long)(n0 + (f0>>5))*K + (f0&31);
  const __hip_bfloat16* Bp1 = B + (long)(n0 + (f1>>5))*K + (f1&31);

  const int nk = K/32;

  GSTAGE(0, 0);
  GSTAGE(1, 1);
  asm volatile("s_waitcnt vmcnt(4)" ::: "memory");   // tile 0 landed
  __builtin_amdgcn_s_barrier();
  __builtin_amdgcn_sched_barrier(0);

  int cur = 0, spc = 2;
  for (int t = 0; t < nk; ++t) {
    if (t + 2 < nk) GSTAGE(t+2, spc);
    __builtin_amdgcn_sched_barrier(0);

    const short* a = As + cur*4096;
    const short* b = Bs + cur*4096;
    short8 af[4], bfm[4];
#pragma unroll
    for (int mi = 0; mi < 4; ++mi)
      af[mi] = *(const short8*)&a[(wrow*64 + mi*16 + l15)*32 + k8];
#pragma unroll
    for (int ni = 0; ni < 4; ++ni)
      bfm[ni] = *(const short8*)&b[(wcol*64 + ni*16 + l15)*32 + k8];
#pragma unroll
    for (int mi = 0; mi < 4; ++mi)
#pragma unroll
      for (int ni = 0; ni < 4; ++ni)
        acc[mi][ni] = __builtin_amdgcn_mfma_f32_16x16x32_bf16(af[mi], bfm[ni], acc[mi][ni], 0, 0, 0);

    if (t + 2 < nk)
      asm volatile("s_waitcnt vmcnt(4) lgkmcnt(0)" ::: "memory");
    else
      asm volatile("s_waitcnt vmcnt(0) lgkmcnt(0)" ::: "memory");
    __builtin_amdgcn_s_barrier();
    __builtin_amdgcn_sched_barrier(0);

    cur = (cur == 2) ? 0 : cur + 1;
    spc = (spc == 2) ? 0 : spc + 1;
  }

  const int rbase = (lane >> 4) * 4;
#pragma unroll
  for (int mi = 0; mi < 4; ++mi)
#pragma unroll
    for (int ni = 0; ni < 4; ++ni) {
      int gm = m0 + wrow*64 + mi*16 + rbase;
      int gn = n0 + wcol*64 + ni*16 + l15;
      float bv = bias[gn];
      float sc = (QSC && gn < HID) ? SCALE2 : 1.0f;
#pragma unroll
      for (int r = 0; r < 4; ++r)
        cvt_store(&C[(long)(gm + r)*N + gn], (acc[mi][ni][r] + bv) * sc);
    }
}

// ---------------- flash attention, KV-split + fixed-max softmax ---------------
// grid (SEQ/128, NH, SPLIT=2) = 768 blocks = exactly 3 blocks/CU, ALL resident
// in a single uniform pass (SPLIT=4's 1536 = 6/CU work over 4 slots = 1.5
// passes with a 25%-occ tail). Atomic combine traffic halves (4->2 adds per
// Oacc elem). Same r13 register schedule — SPLIT is the only change.
// Measured regressions — do not revisit: SPLIT=8 (r6,r11), chain-split QK^T
// (r12), prep-fused zeroing (r12), XCD remap (r14), 4-buffer/VT-after-QKT
// (r14/r15 register spill).
#define ATTN_ITER(T, KSC, KSN, VTC, VTN, MGC, MGN)                              \
  {                                                                             \
    _Pragma("unroll")                                                           \
    for (int e = 0; e < 4; ++e) {                                               \
      unsigned w0 = (unsigned)(unsigned short)va[e] |                           \
                    ((unsigned)(unsigned short)vb[e] << 16);                    \
      *(unsigned*)&(VTN)[(vdb4 + e)*40 + vkv2] = w0;                            \
    }                                                                           \
    if ((T) + 1 < NT)                                                           \
      gload16(kp + (long)((T)+1) * KVB * QKVN, (KSN) + wv*512);                 \
    __builtin_amdgcn_sched_barrier(0);                                          \
    {                                                                           \
      const float* mrowN = mask2 + s0 + ((((T)+1) < NT) ? ((T)+1) : (T))*KVB;   \
      _Pragma("unroll")                                                         \
      for (int g = 0; g < 4; ++g)                                               \
        (MGN)[g] = *(const float4*)(mrowN + 8*g + 4*hi);                        \
      const long kn2 = (long)((((T)+2) < NT) ? ((T)+2) : (NT-1)) * KVB * QKVN;  \
      va = *(const s16x4*)(vsrc + kn2);                                         \
      vb = *(const s16x4*)(vsrc + kn2 + QKVN);                                  \
    }                                                                           \
    short8 kf[4];                                                               \
    _Pragma("unroll")                                                           \
    for (int dc = 0; dc < 4; ++dc)                                              \
      kf[dc] = *(const short8*)&(KSC)[ql*64 + (((dc*2 + hi) ^ (ql & 7))*8)];    \
    f32x16 sacc = {};                                                           \
    _Pragma("unroll")                                                           \
    for (int dc = 0; dc < 4; ++dc)                                              \
      sacc = __builtin_amdgcn_mfma_f32_32x32x16_bf16(kf[dc], qf[dc], sacc, 0, 0, 0); \
    float p[16];                                                                \
    _Pragma("unroll")                                                           \
    for (int g = 0; g < 4; ++g) {                                               \
      p[4*g+0] = EXP2(sacc[4*g+0] + (MGC)[g].x);                                \
      p[4*g+1] = EXP2(sacc[4*g+1] + (MGC)[g].y);                                \
      p[4*g+2] = EXP2(sacc[4*g+2] + (MGC)[g].z);                                \
      p[4*g+3] = EXP2(sacc[4*g+3] + (MGC)[g].w);                                \
    }                                                                           \
    float sl0 = 0.f, sl1 = 0.f;                                                 \
    _Pragma("unroll")                                                           \
    for (int r = 0; r < 8; ++r) { sl0 += p[r]; sl1 += p[8+r]; }                 \
    lrun += sl0 + sl1;                                                          \
    unsigned pk[8];                                                             \
    _Pragma("unroll")                                                           \
    for (int u = 0; u < 8; ++u) pk[u] = cvtpk(p[2*u], p[2*u+1]);                \
    unsigned b0[4], b1[4];                                                      \
    swap32(pk[0], pk[2], b0[0], b0[2]);                                         \
    swap32(pk[1], pk[3], b0[1], b0[3]);                                         \
    swap32(pk[4], pk[6], b1[0], b1[2]);                                         \
    swap32(pk[5], pk[7], b1[1], b1[3]);                                         \
    union UU { unsigned u[4]; short8 s; };                                      \
    UU pb0{{b0[0], b0[1], b0[2], b0[3]}};                                       \
    UU pb1{{b1[0], b1[1], b1[2], b1[3]}};                                       \
    short8 a00 = *(const short8*)&(VTC)[(ql)*40      + hi*8];                   \
    short8 a01 = *(const short8*)&(VTC)[(ql)*40 + 16 + hi*8];                   \
    short8 a10 = *(const short8*)&(VTC)[(32+ql)*40      + hi*8];                \
    short8 a11 = *(const short8*)&(VTC)[(32+ql)*40 + 16 + hi*8];                \
    oacc[0] = __builtin_amdgcn_mfma_f32_32x32x16_bf16(a00, pb0.s, oacc[0], 0, 0, 0); \
    oacc[0] = __builtin_amdgcn_mfma_f32_32x32x16_bf16(a01, pb1.s, oacc[0], 0, 0, 0); \
    oacc[1] = __builtin_amdgcn_mfma_f32_32x32x16_bf16(a10, pb0.s, oacc[1], 0, 0, 0); \
    oacc[1] = __builtin_amdgcn_mfma_f32_32x32x16_bf16(a11, pb1.s, oacc[1], 0, 0, 0); \
    asm volatile("s_waitcnt vmcnt(6) lgkmcnt(0)" ::: "memory");                 \
    __builtin_amdgcn_s_barrier();                                               \
    __builtin_amdgcn_sched_barrier(0);                                          \
  }

__global__ __launch_bounds__(256, 4) void attn_fwd(
    const __hip_bfloat16* __restrict__ QKV,  // [SEQ][2304], Q cols pre-scaled
    const float* __restrict__ mask2,         // [SEQ], pre-scaled by log2e
    float* __restrict__ Oacc,                // [SEQ][HID]  (zeroed)
    float* __restrict__ Lacc)                // [NH][SEQ]   (zeroed)
{
  __shared__ __align__(16) char SMEM[18432];
  short* KsB = (short*)SMEM;            // 2 buffers x 2048 shorts (8KB)
  short* VTB = (short*)(SMEM + 8192);   // 2 buffers x 2560 shorts (10.25KB)
  float* Of  = (float*)SMEM;            // epilogue overlay [64][65] f32 (16.6KB)

  const int tid  = threadIdx.x;
  const int lane = tid & 63;
  const int wv   = tid >> 6;            // 0..3
  const int head = blockIdx.y;
  const int qt   = blockIdx.x;
  const int s0   = blockIdx.z * (SEQ/SPLIT);
  const int q0   = qt*128 + wv*32;
  const int ql   = lane & 31;
  const int hi   = lane >> 5;

  // Q fragments: B-frag for S^T: col=q=ql, k=d = dc*16 + hi*8 + j
  short8 qf[4];
  {
    const __hip_bfloat16* qrow = QKV + (long)(q0+ql)*QKVN + head*HD + hi*8;
#pragma unroll
    for (int dc = 0; dc < 4; ++dc)
      qf[dc] = *(const short8*)(qrow + dc*16);
  }

  // K staging: 256 chunks of 16B, one per thread; LDS chunk (krow,kcs) holds
  // global chunk kcs^(krow&7) (pre-swizzled source, m173).
  const __hip_bfloat16* kp;
  {
    int krow = tid >> 3, kcs = tid & 7;
    kp = QKV + (long)(s0 + krow)*QKVN + HID + head*HD + ((kcs ^ (krow & 7))*8);
  }

  // V staging: thread covers kv-pair (vkv2,vkv2+1), d-slice [vdb4, vdb4+4)
  const int vkv2 = (tid & 15)*2, vdb4 = (tid >> 4)*4;
  const __hip_bfloat16* vsrc = QKV + (long)(s0 + vkv2)*QKVN + 2*HID + head*HD + vdb4;

  f32x16 oacc[2] = {};
  float lrun = 0.0f;
  float4 mgA[4], mgB[4];

  // ---- prologue: VT buf0 <- V[0]; gload K[0]->Ks buf0; prefetch mask[0], V[1] ----
  s16x4 va = *(const s16x4*)(vsrc);
  s16x4 vb = *(const s16x4*)(vsrc + QKVN);
#pragma unroll
  for (int e = 0; e < 4; ++e) {
    unsigned w0 = (unsigned)(unsigned short)va[e] | ((unsigned)(unsigned short)vb[e] << 16);
    *(unsigned*)&VTB[(vdb4 + e)*40 + vkv2] = w0;
  }
  gload16(kp, KsB + wv*512);
  __builtin_amdgcn_sched_barrier(0);
  {
#pragma unroll
    for (int g = 0; g < 4; ++g)
      mgA[g] = *(const float4*)(mask2 + s0 + 8*g + 4*hi);
    const __hip_bfloat16* pv = vsrc + (long)KVB*QKVN;
    va = *(const s16x4*)(pv);
    vb = *(const s16x4*)(pv + QKVN);
  }
  asm volatile("s_waitcnt vmcnt(6) lgkmcnt(0)" ::: "memory");
  __builtin_amdgcn_s_barrier();
  __builtin_amdgcn_sched_barrier(0);

  for (int t = 0; t < NT; t += 2) {
    ATTN_ITER(t,   KsB,        KsB + 2048, VTB,        VTB + 2560, mgA, mgB);
    ATTN_ITER(t+1, KsB + 2048, KsB,        VTB + 2560, VTB,        mgB, mgA);
  }

  // ---- epilogue: O^T -> O transpose via [64][65] overlay, 2 phases ----
  float lp = lrun + __shfl_xor(lrun, 32);
  if (hi == 0)
    unsafeAtomicAdd(&Lacc[head*SEQ + q0 + ql], lp);

#pragma unroll
  for (int ph = 0; ph < 2; ++ph) {
    __syncthreads();
    if ((wv >> 1) == ph) {
      int row = (wv & 1)*32 + ql;
#pragma unroll
      for (int cb = 0; cb < 2; ++cb)
#pragma unroll
        for (int g = 0; g < 4; ++g)
#pragma unroll
          for (int r = 0; r < 4; ++r)
            Of[row*65 + cb*32 + 8*g + 4*hi + r] = oacc[cb][4*g + r];
    }
    __syncthreads();
    float* obase = Oacc + (long)(qt*128 + ph*64)*HID + head*HD + lane;
#pragma unroll 4
    for (int r = 0; r < 16; ++r) {
      int row = wv*16 + r;
      unsafeAtomicAdd(obase + (long)row*HID, Of[row*65 + lane]);
    }
  }
}

// ---------------- finalize: ctx = Oacc / l ------------------------------------
__global__ __launch_bounds__(256) void finalize_kernel(
    const float* __restrict__ Oacc, const float* __restrict__ Lacc,
    __hip_bfloat16* __restrict__ ctx)
{
  int idx = blockIdx.x*256 + threadIdx.x;
  int q  = idx / (HID/4);
  int c4 = (idx - q*(HID/4))*4;
  float inv = 1.0f / Lacc[(c4 >> 6)*SEQ + q];
  float4 o = *(const float4*)&Oacc[(long)q*HID + c4];
  store4(ctx + (long)q*HID + c4, o.x*inv, o.y*inv, o.z*inv, o.w*inv);
}

// ---------------- launcher ----------------------------------------------------
extern "C" void kernel_launch(void* const* d_in, const int* in_sizes, int n_in,
                              void* d_out, int out_size, void* d_ws, size_t ws_size,
                              hipStream_t stream) {
  const float* hs  = (const float*)d_in[0];
  const float* msk = (const float*)d_in[1];
  const float* qw  = (const float*)d_in[2];
  const float* qb  = (const float*)d_in[3];
  const float* kw  = (const float*)d_in[4];
  const float* kb  = (const float*)d_in[5];
  const float* vw  = (const float*)d_in[6];
  const float* vb  = (const float*)d_in[7];
  const float* ow  = (const float*)d_in[8];
  const float* ob  = (const float*)d_in[9];

  char* ws = (char*)d_ws;
  __hip_bfloat16* Xb   = (__hip_bfloat16*)(ws);                 // 6,291,456 B
  __hip_bfloat16* Wqkv = (__hip_bfloat16*)(ws + 6291456);       // 3,538,944 B
  __hip_bfloat16* Wo   = (__hip_bfloat16*)(ws + 9830400);       // 1,179,648 B
  float*          bqkv = (float*)         (ws + 11010048);      //     9,216 B
  __hip_bfloat16* QKV  = (__hip_bfloat16*)(ws + 11019264);      // 18,874,368 B
  __hip_bfloat16* Ctx  = (__hip_bfloat16*)(ws + 29893632);      // 6,291,456 B
  float*          Oacc = (float*)         (ws + 36185088);      // 12,582,912 B
  float*          Lacc = (float*)         (ws + 48768000);      //    196,608 B
  float*          Mask2= (float*)         (ws + 48964608);      //     16,384 B

  hipMemsetAsync(Oacc, 0, 12582912 + 196608, stream);

  {
    const int total = SEQ*HID/4 + QKVN*HID/4 + HID*HID/4 + QKVN/4 + SEQ/4;
    prep_kernel<<<(total + 255)/256, 256, 0, stream>>>(hs, qw, kw, vw, ow, qb, kb, vb, msk,
                                                       Xb, Wqkv, Wo, bqkv, Mask2);
  }
  gemm_nt<__hip_bfloat16, true><<<dim3(QKVN/128, SEQ/128), 256, 0, stream>>>(Xb, Wqkv, bqkv, QKV, QKVN, HID);
  attn_fwd<<<dim3(SEQ/128, NH, SPLIT), 256, 0, stream>>>(QKV, Mask2, Oacc, Lacc);
  finalize_kernel<<<(SEQ*HID/4)/256, 256, 0, stream>>>(Oacc, Lacc, Ctx);
  gemm_nt<float, false><<<dim3(HID/128, SEQ/128), 256, 0, stream>>>(Ctx, Wo, ob, (float*)d_out, HID, HID);
}